// Round 10
// baseline (142.785 us; speedup 1.0000x reference)
//
#include <hip/hip_runtime.h>

#define C_CH 256
#define T_SZ 16
#define H_SZ 64
#define W_SZ 64
#define TGN 5
#define CH 8
#define HWs (H_SZ * W_SZ)          // 4096
#define CSTR (T_SZ * HWs)          // 65536
#define NOUT 196
#define KMAX 10                    // max unique t-slices

__device__ __forceinline__ float2 ld2a(const float* p) {
    const float2* q = (const float2*)__builtin_assume_aligned(p, 8);
    return *q;
}
__device__ __forceinline__ float4 ld4a(const float* p) {
    const float4* q = (const float4*)__builtin_assume_aligned(p, 16);
    return *q;   // gfx950 supports unaligned global loads (addr is 4B-aligned)
}

__global__ __launch_bounds__(256, 8) void roialign3d_kernel(
    const float* __restrict__ features,
    const float* __restrict__ rois,
    float* __restrict__ out)
{
    // XCD-phased decode: 4 super-rounds x (1024 rois x 8 chunk-lanes).
    const int bid   = blockIdx.x;
    const int sr    = bid >> 13;
    const int rem   = bid & 8191;
    const int r     = rem >> 3;
    const int chunk = (sr << 3) | (rem & 7);
    const int c0    = chunk * CH;

    const int tid  = threadIdx.x;
    const int lane = tid & 63;
    const int wid  = __builtin_amdgcn_readfirstlane(tid >> 6);

    __shared__ __align__(16) float sB[KMAX][4];
    __shared__ int sU0, sK;

    const float* roi = rois + r * 7;
    const int   b   = __builtin_amdgcn_readfirstlane((int)roi[0]);
    const float rx1 = roi[1], ry1 = roi[2];
    const float rx2 = roi[4], ry2 = roi[5];

    // ---- t-coefficient table: built once by threads 0..9 ----
    if (tid < KMAX) {
        const float rt1 = roi[3], rt2 = roi[6];
        const float tbin = fmaxf(rt2 - rt1, 0.0f) * 0.25f;
        int t0a[TGN]; float tw0a[TGN], tw1a[TGN];
        #pragma unroll
        for (int i = 0; i < TGN; ++i) {
            float c  = rt1 + tbin * (float)i;
            float lo = fminf(fmaxf(floorf(c), 0.0f), 14.0f);
            float f  = c - lo;
            float v  = (c >= 0.0f && c < 16.0f) ? 0.125f : 0.0f;
            t0a[i]  = (int)lo;
            tw0a[i] = v * (1.0f - f);
            tw1a[i] = v * f;
        }
        const int u0 = t0a[0];
        const int s0 = u0 + tid;
        float av[TGN];
        #pragma unroll
        for (int i = 0; i < TGN; ++i)
            av[i] = (t0a[i] == s0 ? tw0a[i] : 0.0f)
                  + (t0a[i] + 1 == s0 ? tw1a[i] : 0.0f);
        sB[tid][0] = av[0] + av[1];
        sB[tid][1] = av[1] + av[2];
        sB[tid][2] = av[2] + av[3];
        sB[tid][3] = av[3] + av[4];
        if (tid == 0) { sU0 = u0; sK = t0a[TGN - 1] + 2 - u0; }
    }
    __syncthreads();
    const int u0   = __builtin_amdgcn_readfirstlane(sU0);
    const int kcnt = __builtin_amdgcn_readfirstlane(sK);   // in [2, 10]

    const float hs   = ry1 * 0.0625f;
    const float hbin = fmaxf(ry2 * 0.0625f - hs, 0.0f) * (1.0f / 7.0f);
    const float wss  = rx1 * 0.0625f;
    const float wbin = fmaxf(rx2 * 0.0625f - wss, 0.0f) * (1.0f / 7.0f);

    const bool use_fast =
        (bool)__builtin_amdgcn_readfirstlane((int)(wbin <= 2.0f));

    if (use_fast) {
        // ---- fast path: lane = (ch, hg, wpair); 2 gathers per slice ----
        const int ch = lane >> 5;
        const int hg = (lane >> 2) & 7;
        const int wp = lane & 3;
        const int wg0 = wp * 2, wg1 = wg0 + 1;

        // h axis
        const float hc  = hs + hbin * (float)hg;
        const float hlo = fminf(fmaxf(floorf(hc), 0.0f), 62.0f);
        const float hf  = hc - hlo;
        const float hv  = (hc >= 0.0f && hc < 64.0f) ? 1.0f : 0.0f;
        const int   h0  = (int)hlo;
        const float hw0 = hv * (1.0f - hf), hw1 = hv * hf;

        // w axis for two adjacent sample points
        const float wc0 = wss + wbin * (float)wg0;
        const float wl0 = fminf(fmaxf(floorf(wc0), 0.0f), 62.0f);
        const float wf0 = wc0 - wl0;
        const float wv0 = (wc0 >= 0.0f && wc0 < 64.0f) ? 1.0f : 0.0f;
        const int   wi0 = (int)wl0;
        const float A0  = wv0 * (1.0f - wf0), A1 = wv0 * wf0;

        const float wc1 = wss + wbin * (float)wg1;
        const float wl1 = fminf(fmaxf(floorf(wc1), 0.0f), 62.0f);
        const float wf1 = wc1 - wl1;
        const float wv1 = (wc1 >= 0.0f && wc1 < 64.0f) ? 1.0f : 0.0f;
        const int   wi1 = (int)wl1;
        const float B0  = wv1 * (1.0f - wf1), B1 = wv1 * wf1;

        const int base = min(wi0, 60);
        const int p0   = wi0 - base;          // 0..2
        const int p1   = wi1 - base;          // 0..2

        // scatter w-weights into float4 slots (once)
        const float w0v0 = (p0 == 0) ? A0 : 0.0f;
        const float w0v1 = (p0 == 1) ? A0 : ((p0 == 0) ? A1 : 0.0f);
        const float w0v2 = (p0 == 2) ? A0 : ((p0 == 1) ? A1 : 0.0f);
        const float w0v3 = (p0 == 2) ? A1 : 0.0f;
        const float w1v0 = (p1 == 0) ? B0 : 0.0f;
        const float w1v1 = (p1 == 1) ? B0 : ((p1 == 0) ? B1 : 0.0f);
        const float w1v2 = (p1 == 2) ? B0 : ((p1 == 1) ? B1 : 0.0f);
        const float w1v3 = (p1 == 2) ? B1 : 0.0f;

        const float* fc = features
            + ((size_t)b * C_CH + (size_t)(c0 + wid * 2 + ch)) * CSTR
            + (size_t)u0 * HWs + h0 * W_SZ + base;

        float o0[4] = {0.f, 0.f, 0.f, 0.f};
        float o1[4] = {0.f, 0.f, 0.f, 0.f};

        #pragma unroll
        for (int u = 0; u < KMAX; ++u) {
            if (u < 2 || u < kcnt) {
                const float4 bb = *(const float4*)sB[u];
                const float* p = fc + u * HWs;
                float4 fa = ld4a(p);
                float4 fb = ld4a(p + W_SZ);
                const float m0 = hw0 * fa.x + hw1 * fb.x;
                const float m1 = hw0 * fa.y + hw1 * fb.y;
                const float m2 = hw0 * fa.z + hw1 * fb.z;
                const float m3 = hw0 * fa.w + hw1 * fb.w;
                const float bil0 = m0 * w0v0 + m1 * w0v1 + m2 * w0v2 + m3 * w0v3;
                const float bil1 = m0 * w1v0 + m1 * w1v1 + m2 * w1v2 + m3 * w1v3;
                o0[0] += bb.x * bil0; o0[1] += bb.y * bil0;
                o0[2] += bb.z * bil0; o0[3] += bb.w * bil0;
                o1[0] += bb.x * bil1; o1[1] += bb.y * bil1;
                o1[2] += bb.z * bil1; o1[3] += bb.w * bil1;
            }
        }

        // ---- pool: H via shfl 4, W via local + shfl 1; masked stores ----
        float* ob = out + ((size_t)r * C_CH + (size_t)(c0 + wid * 2 + ch)) * NOUT;
        const bool hact = (hg < 7);
        #pragma unroll
        for (int td = 0; td < 4; ++td) {
            float e0 = o0[td] + __shfl_down(o0[td], 4);   // h-pooled, wg0
            float e1 = o1[td] + __shfl_down(o1[td], 4);   // h-pooled, wg1
            float fe = e0 + e1;                            // aw = 2wp
            float fo = e1 + __shfl_down(e0, 1);            // aw = 2wp+1
            if (hact) {
                __builtin_nontemporal_store(fe, &ob[td * 49 + hg * 7 + wg0]);
                if (wp < 3)
                    __builtin_nontemporal_store(fo, &ob[td * 49 + hg * 7 + wg1]);
            }
        }
    } else {
        // ---- fallback (wide roi): R8 path ----
        const int hg = lane >> 3;
        const int wg = lane & 7;

        const float hc  = hs + hbin * (float)hg;
        const float hlo = fminf(fmaxf(floorf(hc), 0.0f), 62.0f);
        const float hf  = hc - hlo;
        const float hv  = (hc >= 0.0f && hc < 64.0f) ? 1.0f : 0.0f;
        const int   h0  = (int)hlo;
        const float hw0 = hv * (1.0f - hf), hw1 = hv * hf;

        const float wc  = wss + wbin * (float)wg;
        const float wlo = fminf(fmaxf(floorf(wc), 0.0f), 62.0f);
        const float wf  = wc - wlo;
        const float wv  = (wc >= 0.0f && wc < 64.0f) ? 1.0f : 0.0f;
        const int   w0  = (int)wlo;
        const float ww0 = wv * (1.0f - wf), ww1 = wv * wf;

        const float w00 = hw0 * ww0, w01 = hw0 * ww1;
        const float w10 = hw1 * ww0, w11 = hw1 * ww1;
        const int hw_off = h0 * W_SZ + w0;

        const float* fcA = features
            + ((size_t)b * C_CH + (size_t)(c0 + wid * 2)) * CSTR
            + (size_t)u0 * HWs + hw_off;
        const float* fcB = fcA + CSTR;

        float oA[4] = {0.f, 0.f, 0.f, 0.f};
        float oB[4] = {0.f, 0.f, 0.f, 0.f};

        #pragma unroll
        for (int u = 0; u < KMAX; ++u) {
            if (u < 2 || u < kcnt) {
                const float4 bb = *(const float4*)sB[u];
                const float* pA = fcA + u * HWs;
                const float* pB = fcB + u * HWs;
                float2 rA0 = ld2a(pA);
                float2 rA1 = ld2a(pA + W_SZ);
                float2 rB0 = ld2a(pB);
                float2 rB1 = ld2a(pB + W_SZ);
                const float bilA = rA0.x * w00 + rA0.y * w01 + rA1.x * w10 + rA1.y * w11;
                const float bilB = rB0.x * w00 + rB0.y * w01 + rB1.x * w10 + rB1.y * w11;
                oA[0] += bb.x * bilA; oA[1] += bb.y * bilA;
                oA[2] += bb.z * bilA; oA[3] += bb.w * bilA;
                oB[0] += bb.x * bilB; oB[1] += bb.y * bilB;
                oB[2] += bb.z * bilB; oB[3] += bb.w * bilB;
            }
        }

        const bool active = (hg < 7) && (wg < 7);
        const int  s_hw   = hg * 7 + wg;
        float* ob = out + ((size_t)r * C_CH + (size_t)(c0 + wid * 2)) * NOUT;
        #pragma unroll
        for (int td = 0; td < 4; ++td) {
            float o = oA[td];
            o += __shfl_down(o, 1);
            o += __shfl_down(o, 8);
            if (active) __builtin_nontemporal_store(o, &ob[td * 49 + s_hw]);
        }
        ob += NOUT;
        #pragma unroll
        for (int td = 0; td < 4; ++td) {
            float o = oB[td];
            o += __shfl_down(o, 1);
            o += __shfl_down(o, 8);
            if (active) __builtin_nontemporal_store(o, &ob[td * 49 + s_hw]);
        }
    }
}

extern "C" void kernel_launch(void* const* d_in, const int* in_sizes, int n_in,
                              void* d_out, int out_size, void* d_ws, size_t ws_size,
                              hipStream_t stream) {
    const float* features = (const float*)d_in[0];
    const float* rois     = (const float*)d_in[1];
    float* out            = (float*)d_out;

    int R = in_sizes[1] / 7;   // 1024
    int nblocks = R * (C_CH / CH);
    hipLaunchKernelGGL(roialign3d_kernel, dim3(nblocks), dim3(256), 0, stream,
                       features, rois, out);
}

// Round 12
// 126.453 us; speedup vs baseline: 1.1292x; 1.1292x over previous
//
#include <hip/hip_runtime.h>

#define C_CH 256
#define T_SZ 16
#define H_SZ 64
#define W_SZ 64
#define TGN 5
#define CH 8
#define HWs (H_SZ * W_SZ)          // 4096
#define CSTR (T_SZ * HWs)          // 65536
#define NOUT 196
#define KMAX 10                    // max unique t-slices

typedef float f32x4 __attribute__((ext_vector_type(4)));

// Single global_load_dwordx2 (addresses are 4B-aligned; HW handles the
// unaligned case; ~1/16 lanes cross a 64B line).
__device__ __forceinline__ float2 ld2a(const float* p) {
    const float2* q = (const float2*)__builtin_assume_aligned(p, 8);
    return *q;
}

__global__ __launch_bounds__(256, 8) void roialign3d_kernel(
    const float* __restrict__ features,
    const float* __restrict__ rois,
    float* __restrict__ out)
{
    // XCD-phased decode: 4 super-rounds x (1024 rois x 8 chunk-lanes).
    const int bid   = blockIdx.x;
    const int sr    = bid >> 13;
    const int rem   = bid & 8191;
    const int r     = rem >> 3;
    const int chunk = (sr << 3) | (rem & 7);
    const int c0    = chunk * CH;

    const int tid  = threadIdx.x;
    const int lane = tid & 63;
    const int wid  = __builtin_amdgcn_readfirstlane(tid >> 6);
    const int hg   = lane >> 3;    // fixed (h,w) grid point per lane
    const int wg   = lane & 7;

    __shared__ __align__(16) float sB[KMAX][4];    // pooled-T coeff per slice
    __shared__ __align__(16) float sOut[CH][NOUT]; // staged outputs (6.3 KB)
    __shared__ int sU0, sK;

    const float* roi = rois + r * 7;
    const int   b   = __builtin_amdgcn_readfirstlane((int)roi[0]);
    const float rx1 = roi[1], ry1 = roi[2];
    const float rx2 = roi[4], ry2 = roi[5];

    // ---- t-coefficient table: built once by threads 0..9 ----
    if (tid < KMAX) {
        const float rt1 = roi[3], rt2 = roi[6];
        const float tbin = fmaxf(rt2 - rt1, 0.0f) * 0.25f;
        int t0a[TGN]; float tw0a[TGN], tw1a[TGN];
        #pragma unroll
        for (int i = 0; i < TGN; ++i) {
            float c  = rt1 + tbin * (float)i;
            float lo = fminf(fmaxf(floorf(c), 0.0f), 14.0f);
            float f  = c - lo;
            float v  = (c >= 0.0f && c < 16.0f) ? 0.125f : 0.0f;  // valid * 1/8
            t0a[i]  = (int)lo;
            tw0a[i] = v * (1.0f - f);
            tw1a[i] = v * f;
        }
        const int u0 = t0a[0];
        const int s0 = u0 + tid;
        float av[TGN];
        #pragma unroll
        for (int i = 0; i < TGN; ++i)
            av[i] = (t0a[i] == s0 ? tw0a[i] : 0.0f)
                  + (t0a[i] + 1 == s0 ? tw1a[i] : 0.0f);
        sB[tid][0] = av[0] + av[1];
        sB[tid][1] = av[1] + av[2];
        sB[tid][2] = av[2] + av[3];
        sB[tid][3] = av[3] + av[4];
        if (tid == 0) { sU0 = u0; sK = t0a[TGN - 1] + 2 - u0; }
    }

    // ---- per-lane h axis ----
    const float hs = ry1 * 0.0625f, he = ry2 * 0.0625f;
    const float hbin = fmaxf(he - hs, 0.0f) * (1.0f / 7.0f);
    const float hc  = hs + hbin * (float)hg;
    const float hlo = fminf(fmaxf(floorf(hc), 0.0f), 62.0f);
    const float hf  = hc - hlo;
    const float hv  = (hc >= 0.0f && hc < 64.0f) ? 1.0f : 0.0f;
    const int   h0  = (int)hlo;
    const float hw0 = hv * (1.0f - hf), hw1 = hv * hf;

    // ---- per-lane w axis ----
    const float wss = rx1 * 0.0625f, wee = rx2 * 0.0625f;
    const float wbin = fmaxf(wee - wss, 0.0f) * (1.0f / 7.0f);
    const float wc  = wss + wbin * (float)wg;
    const float wlo = fminf(fmaxf(floorf(wc), 0.0f), 62.0f);
    const float wf  = wc - wlo;
    const float wv  = (wc >= 0.0f && wc < 64.0f) ? 1.0f : 0.0f;
    const int   w0  = (int)wlo;
    const float ww0 = wv * (1.0f - wf), ww1 = wv * wf;

    const float w00 = hw0 * ww0, w01 = hw0 * ww1;
    const float w10 = hw1 * ww0, w11 = hw1 * ww1;
    const int hw_off = h0 * W_SZ + w0;

    __syncthreads();
    const int u0   = __builtin_amdgcn_readfirstlane(sU0);
    const int kcnt = __builtin_amdgcn_readfirstlane(sK);   // in [2, 10]

    const bool active = (hg < 7) && (wg < 7);
    const int  s_hw   = hg * 7 + wg;

    const float* fcA = features
        + ((size_t)b * C_CH + (size_t)(c0 + wid * 2)) * CSTR
        + (size_t)u0 * HWs + hw_off;
    const float* fcB = fcA + CSTR;

    float oA[4] = {0.f, 0.f, 0.f, 0.f};
    float oB[4] = {0.f, 0.f, 0.f, 0.f};

    #pragma unroll
    for (int u = 0; u < KMAX; ++u) {
        if (u < 2 || u < kcnt) {               // scalar branch (kcnt >= 2)
            const float4 bb = *(const float4*)sB[u];   // uniform broadcast
            const float* pA = fcA + u * HWs;
            const float* pB = fcB + u * HWs;
            float2 rA0 = ld2a(pA);
            float2 rA1 = ld2a(pA + W_SZ);
            float2 rB0 = ld2a(pB);
            float2 rB1 = ld2a(pB + W_SZ);

            const float bilA = rA0.x * w00 + rA0.y * w01 + rA1.x * w10 + rA1.y * w11;
            const float bilB = rB0.x * w00 + rB0.y * w01 + rB1.x * w10 + rB1.y * w11;

            oA[0] += bb.x * bilA; oA[1] += bb.y * bilA;
            oA[2] += bb.z * bilA; oA[3] += bb.w * bilA;
            oB[0] += bb.x * bilB; oB[1] += bb.y * bilB;
            oB[2] += bb.z * bilB; oB[3] += bb.w * bilB;
        }
    }

    // ---- pool W/H via shuffles; stage pooled outputs in LDS ----
    #pragma unroll
    for (int td = 0; td < 4; ++td) {
        float o = oA[td];
        o += __shfl_down(o, 1);
        o += __shfl_down(o, 8);
        if (active) sOut[wid * 2][td * 49 + s_hw] = o;
    }
    #pragma unroll
    for (int td = 0; td < 4; ++td) {
        float o = oB[td];
        o += __shfl_down(o, 1);
        o += __shfl_down(o, 8);
        if (active) sOut[wid * 2 + 1][td * 49 + s_hw] = o;
    }
    __syncthreads();

    // ---- fully-coalesced float4 stores of the block's contiguous region ----
    {
        const f32x4* src = (const f32x4*)&sOut[0][0];          // 392 vec4
        f32x4* dst = (f32x4*)(out + ((size_t)r * C_CH + c0) * NOUT);
        #pragma unroll 2
        for (int i = tid; i < (CH * NOUT) / 4; i += 256)
            __builtin_nontemporal_store(src[i], &dst[i]);
    }
}

extern "C" void kernel_launch(void* const* d_in, const int* in_sizes, int n_in,
                              void* d_out, int out_size, void* d_ws, size_t ws_size,
                              hipStream_t stream) {
    const float* features = (const float*)d_in[0];
    const float* rois     = (const float*)d_in[1];
    float* out            = (float*)d_out;

    int R = in_sizes[1] / 7;   // 1024
    int nblocks = R * (C_CH / CH);
    hipLaunchKernelGGL(roialign3d_kernel, dim3(nblocks), dim3(256), 0, stream,
                       features, rois, out);
}